// Round 6
// baseline (729.468 us; speedup 1.0000x reference)
//
#include <hip/hip_runtime.h>

#define NEGV -1e30f
static constexpr int BATCH = 64;
static constexpr int NN = 512;
static constexpr int MM = 512;
static constexpr int NM = NN * MM;
static constexpr size_t TOTAL = (size_t)BATCH * NM;
static constexpr int NDIAG = NN + MM - 1;            // 1023
static constexpr size_t DBATCH = (size_t)NDIAG * NN; // diag-major floats per batch

// lane n <- lane n-1 (whole-wave shift right by 1), 1 VALU op, no LDS.
__device__ __forceinline__ float wave_shr1(float x) {
    int y = __builtin_amdgcn_mov_dpp(__float_as_int(x), 0x138, 0xf, 0xf, true);
    return __int_as_float(y);
}

// compile-time float4 component select (folds after macro expansion)
#define F4C(v, c) ((c) == 0 ? (v).x : (c) == 1 ? (v).y : (c) == 2 ? (v).z : (v).w)

// ---------------------------------------------------------------------------
// K0: skew-transpose D (row-major) -> D_diag: Dd[b][k*512 + i] = scale*D[b][i][k-i]
// LDS 64x64 tile, stride 66 (diag write Delta=65 === 1 mod 32: conflict-free).
// scale = log2(e) for the base-2 DP (new path) or 1.0 (fallback path).
// ---------------------------------------------------------------------------
__global__ __launch_bounds__(256) void restage_kernel(const float* __restrict__ D,
                                                      float* __restrict__ Dd,
                                                      float scale) {
    __shared__ float tile[64][66];
    const int b = blockIdx.z, it = blockIdx.y, jt = blockIdx.x;
    const float* __restrict__ Db = D + (size_t)b * NM;
    float* __restrict__ Ddb = Dd + (size_t)b * DBATCH;
    const int i0 = it * 64, j0 = jt * 64;
    const int c = threadIdx.x & 63, r0 = threadIdx.x >> 6;
#pragma unroll
    for (int r = r0; r < 64; r += 4)
        tile[r][c] = Db[(size_t)(i0 + r) * MM + j0 + c] * scale;
    __syncthreads();
    for (int kk = r0; kk < 127; kk += 4) {
        const int k = i0 + j0 + kk;
        const int ilo = max(i0, k - (j0 + 63));
        const int ihi = min(i0 + 63, k - j0);
        const int i = ilo + c;
        if (i <= ihi)
            Ddb[(size_t)k * NN + i] = tile[i - i0][k - i - j0];
    }
}

// ---------------------------------------------------------------------------
// K1 (primary, R5): diag-major loads AND diag-major stores. One wave per
// (batch,dir); lane t owns rows [8t,8t+8). Per diagonal: one contiguous 2KB
// wave-load of D_diag, 8 CELLs (base-2 LSE), one contiguous 2KB wave-store of
// np straight from registers (no staging). 4-slot ring, unroll x4. Stores of
// both dirs land in ORIGINAL diag coords (bwd walks K = 1022-k downward).
// ---------------------------------------------------------------------------
template <int DIR>
__device__ __forceinline__ void dp_run2(const float* __restrict__ Ddb,
                                        float* __restrict__ Rdb, int lane) {
    const int i0 = lane * 8;
    const bool l0 = (lane == 0);
    const float dgb0 = l0 ? 0.f : NEGV;
    const int off = DIR ? (504 - i0) : i0;   // element offset within a diag record

    float4 sa0, sb0, sa1, sb1, sa2, sb2, sa3, sb3;

#define LOADSLOT(SL, KARG) do { \
        const ptrdiff_t q_ = DIR ? (ptrdiff_t)(1022 - (KARG)) : (ptrdiff_t)(KARG); \
        const float* a_ = Ddb + q_ * NN + off; \
        sa##SL = *(const float4*)(a_); \
        sb##SL = *(const float4*)(a_ + 4); \
    } while (0)

    LOADSLOT(0, 0); LOADSLOT(1, 1); LOADSLOT(2, 2); LOADSLOT(3, 3);

    // fwd: sa = rows 0..3 (comp c -> r=c), sb = rows 4..7.
    // bwd: sa = {r7,r6,r5,r4}, sb = {r3,r2,r1,r0} (addresses ascend in orig i).
#define DV(r, CA, CB) (DIR ? ((r) < 4 ? F4C(CB, 3 - (r)) : F4C(CA, 7 - (r))) \
                           : ((r) < 4 ? F4C(CA, (r)) : F4C(CB, (r) - 4)))

#define INITP(r) float p1_##r = NEGV, p2_##r = NEGV, np_##r = NEGV;
    INITP(0) INITP(1) INITP(2) INITP(3) INITP(4) INITP(5) INITP(6) INITP(7)

// base-2 LSE cell: val2 = d2 + m2 + log2(1 + 2^(mn-m) + 2^(md-m))
#define CELL(r, DGIN, UPIN, DGB, CA, CB) do { \
        const int j_ = jj - (r); \
        const bool jz_ = (j_ == 0); \
        const float dg_ = jz_ ? (DGB) : (DGIN); \
        const float up_ = (UPIN); \
        const float lf_ = jz_ ? NEGV : p1_##r; \
        const float m_  = fmaxf(fmaxf(dg_, up_), lf_); \
        const float mn_ = fminf(fminf(dg_, up_), lf_); \
        const float md_ = __builtin_amdgcn_fmed3f(dg_, up_, lf_); \
        const float s_  = 1.f + __builtin_exp2f(mn_ - m_) + __builtin_exp2f(md_ - m_); \
        np_##r = DV(r, CA, CB) + m_ + __builtin_log2f(s_); \
    } while (0)

#define SHIFT(r) do { p2_##r = p1_##r; p1_##r = np_##r; } while (0)

#define STEP(KK) do { \
        const int k = kb + (KK); \
        const int jj = k - i0; \
        const float4 ca_ = sa##KK, cb_ = sb##KK; \
        LOADSLOT(KK, k + 4); \
        const float ups_ = wave_shr1(p1_7); \
        const float dgs_ = wave_shr1(p2_7); \
        const float up0r = l0 ? NEGV : ups_; \
        const float dg0r = l0 ? NEGV : dgs_; \
        CELL(0, dg0r, up0r, dgb0, ca_, cb_); \
        CELL(1, p2_0, p1_0, NEGV, ca_, cb_); \
        CELL(2, p2_1, p1_1, NEGV, ca_, cb_); \
        CELL(3, p2_2, p1_2, NEGV, ca_, cb_); \
        CELL(4, p2_3, p1_3, NEGV, ca_, cb_); \
        CELL(5, p2_4, p1_4, NEGV, ca_, cb_); \
        CELL(6, p2_5, p1_5, NEGV, ca_, cb_); \
        CELL(7, p2_6, p1_6, NEGV, ca_, cb_); \
        if (jj >= 0 && jj <= 518) { \
            const ptrdiff_t q_ = DIR ? (ptrdiff_t)(1022 - k) : (ptrdiff_t)k; \
            float* a_ = Rdb + q_ * NN + off; \
            if (!DIR) { \
                *(float4*)(a_)     = make_float4(np_0, np_1, np_2, np_3); \
                *(float4*)(a_ + 4) = make_float4(np_4, np_5, np_6, np_7); \
            } else { \
                *(float4*)(a_)     = make_float4(np_7, np_6, np_5, np_4); \
                *(float4*)(a_ + 4) = make_float4(np_3, np_2, np_1, np_0); \
            } \
        } \
        SHIFT(0); SHIFT(1); SHIFT(2); SHIFT(3); \
        SHIFT(4); SHIFT(5); SHIFT(6); SHIFT(7); \
    } while (0)

    for (int kb = 0; kb < NN + MM; kb += 4) {
        STEP(0); STEP(1); STEP(2); STEP(3);
    }
#undef LOADSLOT
#undef DV
#undef INITP
#undef CELL
#undef SHIFT
#undef STEP
}

__global__ __launch_bounds__(64, 1) void dp_kernel2(const float* __restrict__ Dd,
                                                    float* __restrict__ Fd,
                                                    float* __restrict__ Bd) {
    const int blk = blockIdx.x;
    const int b = blk & (BATCH - 1);
    const int dir = blk >> 6;
    const float* Ddb = Dd + (size_t)b * DBATCH;
    const int lane = threadIdx.x;
    if (dir) dp_run2<1>(Ddb, Bd + (size_t)b * DBATCH, lane);
    else     dp_run2<0>(Ddb, Fd + (size_t)b * DBATCH, lane);
}

// ---------------------------------------------------------------------------
// tail helpers
// ---------------------------------------------------------------------------
__device__ inline float blockMax256(float v) {
    __shared__ float sm[256];
    sm[threadIdx.x] = v;
    __syncthreads();
    for (int s = 128; s > 0; s >>= 1) {
        if ((int)threadIdx.x < s)
            sm[threadIdx.x] = fmaxf(sm[threadIdx.x], sm[threadIdx.x + s]);
        __syncthreads();
    }
    return sm[0];
}

// K2 (R5): de-skew f_diag+b_diag -> row-major, fuse logit = ln2*(f2+b2) - d,
// per-block max partials. LDS tile stride 66: diag write conflict-free.
__global__ __launch_bounds__(256) void deskew_logit_kernel(
        const float* __restrict__ Fd, const float* __restrict__ Bd,
        const float* __restrict__ D, float* __restrict__ out,
        float* __restrict__ partial) {
    __shared__ float tile[64][66];
    const int b = blockIdx.z, it = blockIdx.y, jt = blockIdx.x;
    const size_t dbase = (size_t)b * DBATCH;
    const float* __restrict__ Fb = Fd + dbase;
    const float* __restrict__ Bb = Bd + dbase;
    const int i0 = it * 64, j0 = jt * 64;
    const int c = threadIdx.x & 63, r0 = threadIdx.x >> 6;
    for (int kk = r0; kk < 127; kk += 4) {
        const int k = i0 + j0 + kk;
        const int ilo = max(i0, k - (j0 + 63));
        const int ihi = min(i0 + 63, k - j0);
        const int i = ilo + c;
        if (i <= ihi) {
            const size_t o = (size_t)k * NN + i;
            tile[i - i0][k - i - j0] = Fb[o] + Bb[o];
        }
    }
    __syncthreads();
    const float* __restrict__ Db = D + (size_t)b * NM;
    float* __restrict__ ob = out + (size_t)b * NM;
    float mx = NEGV;
#pragma unroll
    for (int r = r0; r < 64; r += 4) {
        const size_t o = (size_t)(i0 + r) * MM + j0 + c;
        const float v = tile[r][c] * 0.6931471805599453f - Db[o];
        ob[o] = v;
        mx = fmaxf(mx, v);
    }
    float bm = blockMax256(mx);
    if (threadIdx.x == 0)
        partial[blockIdx.x + gridDim.x * (blockIdx.y + gridDim.y * blockIdx.z)] = bm;
}

__global__ __launch_bounds__(256) void finalmax_kernel(const float* __restrict__ partial,
                                                       int n,
                                                       float* __restrict__ outmax) {
    float mx = NEGV;
    for (int i = threadIdx.x; i < n; i += 256) mx = fmaxf(mx, partial[i]);
    float bm = blockMax256(mx);
    if (threadIdx.x == 0) *outmax = bm;
}

__global__ __launch_bounds__(256) void sub_kernel(float4* __restrict__ out,
                                                  const float* __restrict__ maxp) {
    const float mx = *maxp;
    const size_t n4 = TOTAL / 4;
    const size_t stride = (size_t)gridDim.x * blockDim.x;
    for (size_t idx = (size_t)blockIdx.x * blockDim.x + threadIdx.x; idx < n4;
         idx += stride) {
        float4 v = out[idx];
        v.x -= mx; v.y -= mx; v.z -= mx; v.w -= mx;
        out[idx] = v;
    }
}

// ---------------------------------------------------------------------------
// Fallback path (R4, proven): diag loads + row-major stores; base-e.
// ---------------------------------------------------------------------------
template <int DIR>
__device__ __forceinline__ void dp_run_diag(const float* __restrict__ Dd,
                                            float* __restrict__ Rp, int lane) {
    const int i0 = lane * 8;
    const bool l0 = (lane == 0);
    const float dgb0 = l0 ? 0.f : NEGV;

#define PTRS(r) \
    float* stp_##r = DIR ? (Rp + (size_t)(NM - 1) - (size_t)(i0 + r) * MM) \
                         : (Rp + (size_t)(i0 + r) * MM);
    PTRS(0) PTRS(1) PTRS(2) PTRS(3) PTRS(4) PTRS(5) PTRS(6) PTRS(7)

    const float* cur;
    float4 s0a, s0b, s1a, s1b;
    if (!DIR) {
        const float* P = Dd + i0;
        s0a = *(const float4*)(P);      s0b = *(const float4*)(P + 4);
        s1a = *(const float4*)(P + NN); s1b = *(const float4*)(P + NN + 4);
        cur = P + 2 * NN;
    } else {
        const float* P = Dd + 504 - i0;
        s0a = *(const float4*)(P + (size_t)NN * 1022 + 4); s0b = *(const float4*)(P + (size_t)NN * 1022);
        s1a = *(const float4*)(P + (size_t)NN * 1021 + 4); s1b = *(const float4*)(P + (size_t)NN * 1021);
        cur = P + (size_t)NN * 1020;
    }

#define DVO(r, CA, CB) (DIR ? ((r) < 4 ? F4C(CA, 3 - (r)) : F4C(CB, 7 - (r))) \
                            : ((r) < 4 ? F4C(CA, (r)) : F4C(CB, (r) - 4)))
#define INITPO(r) float p1_##r = NEGV, p2_##r = NEGV, p3_##r = NEGV, np_##r = NEGV;
    INITPO(0) INITPO(1) INITPO(2) INITPO(3) INITPO(4) INITPO(5) INITPO(6) INITPO(7)

#define CELLO(r, DGIN, UPIN, DGB, CA, CB) do { \
        const int j_ = jj - (r); \
        const bool jz_ = (j_ == 0); \
        const float dg_ = jz_ ? (DGB) : (DGIN); \
        const float up_ = (UPIN); \
        const float lf_ = jz_ ? NEGV : p1_##r; \
        const float m_  = fmaxf(fmaxf(dg_, up_), lf_); \
        const float mn_ = fminf(fminf(dg_, up_), lf_); \
        const float md_ = __builtin_amdgcn_fmed3f(dg_, up_, lf_); \
        const float s_  = 1.f + __expf(mn_ - m_) + __expf(md_ - m_); \
        np_##r = DVO(r, CA, CB) + m_ + __logf(s_); \
    } while (0)

#define STOREO(r) do { \
        const int j_ = jj - (r); \
        if (j_ >= 3 && j_ < MM) { \
            if (DIR) *(float4*)(stp_##r - j_) = \
                make_float4(np_##r, p1_##r, p2_##r, p3_##r); \
            else     *(float4*)(stp_##r + j_ - 3) = \
                make_float4(p3_##r, p2_##r, p1_##r, np_##r); \
        } \
    } while (0)

#define SHIFTO(r) do { p3_##r = p2_##r; p2_##r = p1_##r; p1_##r = np_##r; } while (0)

#define STEPO(KK, SL, SA, SB) do { \
        const int jj = kbj + (KK); \
        const float4 ca_ = s##SL##a, cb_ = s##SL##b; \
        if (!DIR) { s##SL##a = *(const float4*)(cur); \
                    s##SL##b = *(const float4*)(cur + 4); cur += NN; } \
        else      { s##SL##a = *(const float4*)(cur + 4); \
                    s##SL##b = *(const float4*)(cur); cur -= NN; } \
        const float ups_ = wave_shr1(p1_7); \
        const float dgs_ = wave_shr1(p2_7); \
        const float up0r = l0 ? NEGV : ups_; \
        const float dg0r = l0 ? NEGV : dgs_; \
        CELLO(0, dg0r, up0r, dgb0, ca_, cb_); \
        CELLO(1, p2_0, p1_0, NEGV, ca_, cb_); \
        CELLO(2, p2_1, p1_1, NEGV, ca_, cb_); \
        CELLO(3, p2_2, p1_2, NEGV, ca_, cb_); \
        CELLO(4, p2_3, p1_3, NEGV, ca_, cb_); \
        CELLO(5, p2_4, p1_4, NEGV, ca_, cb_); \
        CELLO(6, p2_5, p1_5, NEGV, ca_, cb_); \
        CELLO(7, p2_6, p1_6, NEGV, ca_, cb_); \
        STOREO(SA); STOREO(SB); \
        SHIFTO(0); SHIFTO(1); SHIFTO(2); SHIFTO(3); \
        SHIFTO(4); SHIFTO(5); SHIFTO(6); SHIFTO(7); \
    } while (0)

    for (int kb = 0; kb < NN + MM; kb += 4) {
        const int kbj = kb - i0;
        STEPO(0, 0, 1, 5);
        STEPO(1, 1, 2, 6);
        STEPO(2, 0, 3, 7);
        STEPO(3, 1, 0, 4);
    }
#undef PTRS
#undef DVO
#undef INITPO
#undef CELLO
#undef STOREO
#undef SHIFTO
#undef STEPO
}

__global__ __launch_bounds__(64, 1) void dp_kernel_diag(const float* __restrict__ Dd,
                                                        float* __restrict__ Rf,
                                                        float* __restrict__ Rb) {
    const int blk = blockIdx.x;
    const int b = blk & (BATCH - 1);
    const int dir = blk >> 6;
    const float* __restrict__ Ddb = Dd + (size_t)b * DBATCH;
    const int lane = threadIdx.x;
    if (dir) dp_run_diag<1>(Ddb, Rb + (size_t)b * NM, lane);
    else     dp_run_diag<0>(Ddb, Rf + (size_t)b * NM, lane);
}

__global__ __launch_bounds__(256) void logit_kernel(const float4* __restrict__ D,
                                                    const float4* __restrict__ Rb,
                                                    float4* __restrict__ out,
                                                    float* __restrict__ partial) {
    const size_t n4 = TOTAL / 4;
    float mx = NEGV;
    const size_t stride = (size_t)gridDim.x * blockDim.x;
    for (size_t idx = (size_t)blockIdx.x * blockDim.x + threadIdx.x; idx < n4;
         idx += stride) {
        float4 f = out[idx], bb = Rb[idx], d = D[idx];
        float4 v = make_float4(f.x + bb.x - d.x, f.y + bb.y - d.y,
                               f.z + bb.z - d.z, f.w + bb.w - d.w);
        out[idx] = v;
        mx = fmaxf(mx, fmaxf(fmaxf(v.x, v.y), fmaxf(v.z, v.w)));
    }
    float bm = blockMax256(mx);
    if (threadIdx.x == 0) partial[blockIdx.x] = bm;
}

extern "C" void kernel_launch(void* const* d_in, const int* in_sizes, int n_in,
                              void* d_out, int out_size, void* d_ws, size_t ws_size,
                              hipStream_t stream) {
    const float* D = (const float*)d_in[0];
    float* out = (float*)d_out;
    float* ws_f = (float*)d_ws;

    const size_t DB64 = (size_t)BATCH * DBATCH;

    // New-path layout: [pad 4096][Dd][pad 4096][Fd][Bd][partial 4096][maxp]
    float* Dd2 = ws_f + 4096;
    float* Fd = Dd2 + DB64 + 4096;
    float* Bd = Fd + DB64;
    float* partial2 = Bd + DB64;
    float* maxp2 = partial2 + 4096;
    const size_t need_new = (4096 + DB64 + 4096 + DB64 + DB64 + 4096 + 16)
                            * sizeof(float);

    if (ws_size >= need_new) {
        restage_kernel<<<dim3(8, 8, 64), 256, 0, stream>>>(D, Dd2,
                                                           1.4426950408889634f);
        dp_kernel2<<<128, 64, 0, stream>>>(Dd2, Fd, Bd);
        deskew_logit_kernel<<<dim3(8, 8, 64), 256, 0, stream>>>(Fd, Bd, D, out,
                                                                partial2);
        finalmax_kernel<<<1, 256, 0, stream>>>(partial2, 4096, maxp2);
        sub_kernel<<<2048, 256, 0, stream>>>((float4*)out, maxp2);
    } else {
        // Fallback: R4 layout/path
        float* Rb = ws_f;
        float* partial = ws_f + TOTAL;
        float* maxp = partial + 4096;
        float* Dd = ws_f + TOTAL + 8192;
        restage_kernel<<<dim3(8, 8, 64), 256, 0, stream>>>(D, Dd, 1.0f);
        dp_kernel_diag<<<128, 64, 0, stream>>>(Dd, out, Rb);
        logit_kernel<<<2048, 256, 0, stream>>>((const float4*)D, (const float4*)Rb,
                                               (float4*)out, partial);
        finalmax_kernel<<<1, 256, 0, stream>>>(partial, 2048, maxp);
        sub_kernel<<<2048, 256, 0, stream>>>((float4*)out, maxp);
    }
}